// Round 11
// baseline (82.359 us; speedup 1.0000x reference)
//
#include <hip/hip_runtime.h>
#include <math.h>
#include <stdint.h>

#define IMGS 64
#define HWDIM 512
#define KLEN 31
#define RAD 15
#define EPSV 1e-3f
#define MM_STRIDE 32   // ints per image slot (one 128B cache line each)

// ws layout (floats):
//   [0..31)     : separable weights s[i]  (kernel[i][j] = s_i*s_j)
//   [32..2080)  : per-image min/max int bits, 32-int stride
// d_out carries the pre-norm conv result, normalized in place by final_k.

typedef __attribute__((address_space(3))) uint8_t  lds_u8;
typedef const __attribute__((address_space(1))) uint8_t g_u8;

// XOR-8 swizzle of 16B slots within a row (involution; stays inside the
// 128B-aligned 8-slot group -> DMA cache-line coalescing preserved).
__device__ __forceinline__ int swz8(int s, int rx) {
    return (s & ~7) | ((s & 7) ^ rx);
}

__global__ __launch_bounds__(128) void init_k(const float* __restrict__ gk,
                                              float* __restrict__ w,
                                              int* __restrict__ mm) {
    int t = threadIdx.x;
    if (t < KLEN) w[t] = sqrtf(gk[t * KLEN + t]);   // diag of s_i*s_j = s_i^2
    if (t < IMGS) { mm[t * MM_STRIDE] = 0x7F800000; mm[t * MM_STRIDE + 1] = 0; }
}

// phase A item: row r (0..93), quarter q (0..3) -> 16 h-conv outputs,
// computed in place inside the raw LDS tile (row-local; same-wave lockstep
// makes read-before-write safe without barriers).
template <bool EDGE>
__device__ __forceinline__ void itemA(int i, int x0, int y0,
                                      const float* __restrict__ wg,
                                      float* __restrict__ raw) {
    const int r = i >> 2, q = i & 3, rx = r & 7;
    const int sb = q << 2;                       // first logical window slot
    float4 b[12];
#pragma unroll
    for (int m = 0; m < 12; ++m)
        b[m] = *(const float4*)&raw[(r * 24 + swz8(sb + m, rx)) << 2];
    const int y = y0 - RAD + r;
    const bool vy = !EDGE || ((unsigned)y < HWDIM);
    const int gb = (x0 >> 2) - 4 + sb;
    float vv[48];
#pragma unroll
    for (int m = 0; m < 12; ++m) {
        const bool vx = !EDGE || (vy && ((unsigned)(gb + m) < 128u));
        vv[4 * m + 0] = vx ? fminf(fmaxf(b[m].x, 0.f), 1.f) : 0.f;  // v_med3
        vv[4 * m + 1] = vx ? fminf(fmaxf(b[m].y, 0.f), 1.f) : 0.f;
        vv[4 * m + 2] = vx ? fminf(fmaxf(b[m].z, 0.f), 1.f) : 0.f;
        vv[4 * m + 3] = vx ? fminf(fmaxf(b[m].w, 0.f), 1.f) : 0.f;
    }
#pragma unroll
    for (int d = 0; d < 4; ++d) {
        float4 o;
        float* op = &o.x;
#pragma unroll
        for (int s = 0; s < 4; ++s) {
            const int oc = (d << 2) + s;
            float a = 0.f;
#pragma unroll
            for (int k = 0; k < KLEN; ++k) a += vv[oc + 1 + k] * wg[k];
            op[s] = a;
        }
        // output cols q*16+d*4.. -> logical slot 4 + q*4 + d
        *(float4*)&raw[(r * 24 + swz8(4 + sb + d, rx)) << 2] = o;
    }
}

// Fused separable 31x31 conv per 64x64 output tile.
// DMA-stage raw 94x96 tile (XOR-8 swizzled via pre-swizzled source addrs),
// hconv in place, vconv from LDS -> pre-norm out + per-image min/max.
template <bool EDGE>
__device__ __forceinline__ void conv_body(const float* __restrict__ attn,
                                          float* __restrict__ out,
                                          const float* __restrict__ wg,
                                          int* __restrict__ mm,
                                          int img, int x0, int y0,
                                          float* __restrict__ raw,
                                          float* __restrict__ sred) {
    const int t = threadIdx.x;
    const float* src = attn + ((size_t)img << 18);

    // ---- DMA stage: 2256 16B slots (94 rows x 24), linear LDS dest,
    //      source pre-swizzled; OOB sources clamped (masked in compute). ----
    const int gbq = (x0 >> 2) - 4;
#pragma unroll
    for (int it = 0; it < 9; ++it) {
        const int i  = t + (it << 8);
        const int ic = i < 2255 ? i : 2255;      // dup tail into pad slots
        const int r   = ic / 24;
        const int c4p = ic - r * 24;
        const int c4l = (c4p & ~7) | ((c4p & 7) ^ (r & 7));
        int y = y0 - RAD + r;
        y = y < 0 ? 0 : (y > HWDIM - 1 ? HWDIM - 1 : y);
        int g4 = gbq + c4l;
        g4 = g4 < 0 ? 0 : (g4 > 127 ? 127 : g4);
        const float* gp = src + ((size_t)y << 9) + (g4 << 2);
        __builtin_amdgcn_global_load_lds((g_u8*)gp, (lds_u8*)&raw[i << 2], 16, 0, 0);
    }
    __syncthreads();                             // drains vmcnt

    // ---- phase A: 376 items; rows are wave-exclusive -> no extra barrier ----
    itemA<EDGE>(t, x0, y0, wg, raw);
    if (t < 120) itemA<EDGE>(256 + t, x0, y0, wg, raw);
    __syncthreads();

    // ---- phase B: vconv, each thread owns a 4-col x 4-row patch ----
    const int tx = t & 15;
    const int ty = t >> 4;
    float4 acc[4];
#pragma unroll
    for (int i = 0; i < 4; ++i) acc[i] = make_float4(0.f, 0.f, 0.f, 0.f);
#pragma unroll
    for (int k = 0; k < 34; ++k) {
        const int row = (ty << 2) + k;
        const float4 v = *(const float4*)&raw[(row * 24 + swz8(4 + tx, row & 7)) << 2];
#pragma unroll
        for (int i = 0; i < 4; ++i) {
            const int j = k - i;                 // weight index, compile-time
            if (j >= 0 && j < KLEN) {
                const float w = wg[j];
                acc[i].x += v.x * w;
                acc[i].y += v.y * w;
                acc[i].z += v.z * w;
                acc[i].w += v.w * w;
            }
        }
    }
    float* dst = out + ((size_t)img << 18);
    float lmin = INFINITY, lmax = -INFINITY;
#pragma unroll
    for (int i = 0; i < 4; ++i) {
        *(float4*)&dst[(size_t)(y0 + (ty << 2) + i) * HWDIM + x0 + (tx << 2)] = acc[i];
        lmin = fminf(lmin, fminf(fminf(acc[i].x, acc[i].y), fminf(acc[i].z, acc[i].w)));
        lmax = fmaxf(lmax, fmaxf(fmaxf(acc[i].x, acc[i].y), fmaxf(acc[i].z, acc[i].w)));
    }
    // wave butterfly -> block LDS reduce -> one atomic pair per block
#pragma unroll
    for (int off = 1; off < 64; off <<= 1) {
        lmin = fminf(lmin, __shfl_xor(lmin, off, 64));
        lmax = fmaxf(lmax, __shfl_xor(lmax, off, 64));
    }
    const int lane = t & 63, wid = t >> 6;
    if (lane == 0) { sred[wid] = lmin; sred[4 + wid] = lmax; }
    __syncthreads();
    if (t == 0) {
        float bmin = fminf(fminf(sred[0], sred[1]), fminf(sred[2], sred[3]));
        float bmax = fmaxf(fmaxf(sred[4], sred[5]), fmaxf(sred[6], sred[7]));
        // all values >= 0 -> float ordering == int-bits ordering
        atomicMin(&mm[img * MM_STRIDE], __float_as_int(bmin));
        atomicMax(&mm[img * MM_STRIDE + 1], __float_as_int(bmax));
    }
}

__global__ __launch_bounds__(256) void conv_k(const float* __restrict__ attn,
                                              float* __restrict__ out,
                                              const float* __restrict__ wg,
                                              int* __restrict__ mm) {
    __shared__ float raw[2304 * 4];              // 94x24 slots + DMA pad = 36.9 KB
    __shared__ float sred[8];
    // XCD swizzle: XCD k (bid&7) gets 512 contiguous work items = 8 whole
    // images -> halo re-reads stay in that XCD's L2.
    const int sw  = ((blockIdx.x & 7) << 9) + (blockIdx.x >> 3);
    const int img = sw >> 6;
    const int by  = (sw >> 3) & 7;
    const int bx  = sw & 7;
    const int x0 = bx << 6;
    const int y0 = by << 6;
    if (bx == 0 || bx == 7 || by == 0 || by == 7)
        conv_body<true>(attn, out, wg, mm, img, x0, y0, raw, sred);
    else
        conv_body<false>(attn, out, wg, mm, img, x0, y0, raw, sred);
}

// out = max((out - mn) / max(mx - mn, eps), clip(attn,0,1)), in place.
__global__ __launch_bounds__(256) void final_k(const float* __restrict__ attn,
                                               float* __restrict__ out,
                                               const int* __restrict__ mm) {
    const int img = blockIdx.x >> 6;             // 64 blocks of 4096 elems/image
    const float mn = __int_as_float(mm[img * MM_STRIDE]);
    const float mx = __int_as_float(mm[img * MM_STRIDE + 1]);
    const float inv = 1.0f / fmaxf(mx - mn, EPSV);
    const size_t base0 = ((size_t)blockIdx.x << 12) + ((size_t)threadIdx.x << 2);
#pragma unroll
    for (int h = 0; h < 4; ++h) {
        const size_t base = base0 + (size_t)h * 1024;
        float4 s = *(const float4*)(out + base);
        float4 a = *(const float4*)(attn + base);
        float4 o;
        o.x = fmaxf((s.x - mn) * inv, fminf(fmaxf(a.x, 0.f), 1.f));
        o.y = fmaxf((s.y - mn) * inv, fminf(fmaxf(a.y, 0.f), 1.f));
        o.z = fmaxf((s.z - mn) * inv, fminf(fmaxf(a.z, 0.f), 1.f));
        o.w = fmaxf((s.w - mn) * inv, fminf(fmaxf(a.w, 0.f), 1.f));
        *(float4*)(out + base) = o;
    }
}

extern "C" void kernel_launch(void* const* d_in, const int* in_sizes, int n_in,
                              void* d_out, int out_size, void* d_ws, size_t ws_size,
                              hipStream_t stream) {
    const float* attn = (const float*)d_in[0];
    const float* gk   = (const float*)d_in[1];
    float* out  = (float*)d_out;
    float* wsf  = (float*)d_ws;
    float* w1d  = wsf;
    int*   mm   = (int*)(wsf + 32);

    init_k<<<1, 128, 0, stream>>>(gk, w1d, mm);
    conv_k<<<4096, 256, 0, stream>>>(attn, out, w1d, mm);
    final_k<<<IMGS * HWDIM * HWDIM / 4096, 256, 0, stream>>>(attn, out, mm);
}